// Round 3
// baseline (999.333 us; speedup 1.0000x reference)
//
#include <hip/hip_runtime.h>

typedef __bf16 bf16x8 __attribute__((ext_vector_type(8)));
typedef float f32x4 __attribute__((ext_vector_type(4)));

#define DFEAT 128
#define HDIM 64
#define IDX_BITS 21
#define IDX_MASK ((1u << IDX_BITS) - 1)
#define EMPTY_SLOT 0xFFFFFFFFFFFFFFFFull

// fast shifted-softplus: log(1+e^x) - log2, via native v_exp_f32/v_log_f32 (~7 VALU ops)
__device__ __forceinline__ float ssp_fast(float x) {
    float m = fmaxf(x, 0.0f);
    float t = __expf(-fabsf(x));
    return m + __logf(1.0f + t) - 0.69314718055994531f;
}

// edge_index may arrive as int32 (harness contract) or int64 (reference dtype).
// Detect at runtime: int64 layout has all-zero odd dwords (values < 2^31).
__global__ void detect_idx_kernel(const unsigned int* __restrict__ p, int n_check,
                                  unsigned int* __restrict__ flag_any) {
    unsigned int acc = 0;
    for (int i = threadIdx.x; i < n_check; i += blockDim.x)
        acc |= p[2 * i + 1];
    if (acc) atomicOr(flag_any, 1u);
}

__device__ __forceinline__ int load_idx(const void* p, int is64, long long i) {
    if (is64) return (int)((const long long*)p)[i];
    return ((const int*)p)[i];
}

// Kernel A: per-edge MLP via split-bf16 MFMA (Ah*Wh + Al*Wh + Ah*Wl, ~2^-16 rel err).
// B hi/lo fragment tables live in LDS (32 KB) to avoid the round-2 register spill.
// Wave = 16 edges x 64 hidden, K=128 in 4 k-chunks.
__global__ __launch_bounds__(256, 4) void mlp_mag_kernel(
    const float* __restrict__ feats,
    const void* __restrict__ eidx,
    const float* __restrict__ w1,
    const float* __restrict__ b1,
    const float* __restrict__ w2,
    const float* __restrict__ b2,
    float* __restrict__ mag_raw,
    float* __restrict__ csum,
    float* __restrict__ ccnt,
    const unsigned int* __restrict__ flag_any,
    int E)
{
    __shared__ __align__(16) unsigned char smem[32768];
    float* w1s = (float*)smem;                       // transient: raw w1 (32 KB)
    bf16x8* hiTab = (bf16x8*)smem;                   // final: hi frags (16 KB)
    bf16x8* loTab = (bf16x8*)(smem + 16384);         // final: lo frags (16 KB)

    const int is64 = (flag_any[0] == 0u) ? 1 : 0;
    const int lane = threadIdx.x & 63;
    const int r = lane & 15;   // A-row (edge) / C-col index
    const int g = lane >> 4;   // k-group
    const int wave = blockIdx.x * (blockDim.x >> 6) + (threadIdx.x >> 6);
    const int nwaves = gridDim.x * (blockDim.x >> 6);

    // --- Stage B fragment tables in LDS (once per block) ---
    for (int idx = threadIdx.x; idx < DFEAT * HDIM / 4; idx += blockDim.x)
        ((float4*)w1s)[idx] = ((const float4*)w1)[idx];
    __syncthreads();

    {
        const int tkt = threadIdx.x >> 6;   // this thread builds frags for k-chunk tkt
        const int tl = threadIdx.x & 63;
        const int tg = tl >> 4, tr = tl & 15;
        float vals[4][8];
#pragma unroll
        for (int nt = 0; nt < 4; ++nt)
#pragma unroll
            for (int i = 0; i < 8; ++i)
                vals[nt][i] = w1s[(tkt * 32 + tg * 8 + i) * HDIM + nt * 16 + tr];
        __syncthreads();   // done reading raw w1; safe to overwrite
#pragma unroll
        for (int nt = 0; nt < 4; ++nt) {
            bf16x8 h, lo;
#pragma unroll
            for (int i = 0; i < 8; ++i) {
                float w = vals[nt][i];
                __bf16 hi = (__bf16)w;
                h[i] = hi;
                lo[i] = (__bf16)(w - (float)hi);
            }
            hiTab[(tkt * 4 + nt) * 64 + tl] = h;
            loTab[(tkt * 4 + nt) * 64 + tl] = lo;
        }
        __syncthreads();
    }

    float b1v[4], w2v[4];
#pragma unroll
    for (int nt = 0; nt < 4; ++nt) {
        b1v[nt] = b1[nt * 16 + r];
        w2v[nt] = w2[nt * 16 + r];
    }
    const float b2v = b2[0];

    const int ntiles = (E + 15) >> 4;
    for (int tile = wave; tile < ntiles; tile += nwaves) {
        const int e0 = tile << 4;
        const int erow = e0 + r;

        // This lane's 32 feature floats (8 x float4), coalesced per row.
        float4 av[8];
        if (erow < E) {
            const float4* fp = (const float4*)(feats + (size_t)erow * DFEAT);
#pragma unroll
            for (int kt = 0; kt < 4; ++kt) {
                av[kt * 2 + 0] = fp[kt * 8 + g * 2 + 0];
                av[kt * 2 + 1] = fp[kt * 8 + g * 2 + 1];
            }
        } else {
#pragma unroll
            for (int q = 0; q < 8; ++q) av[q] = make_float4(0.f, 0.f, 0.f, 0.f);
        }

        f32x4 acc[4] = {{0.f,0.f,0.f,0.f},{0.f,0.f,0.f,0.f},{0.f,0.f,0.f,0.f},{0.f,0.f,0.f,0.f}};
#pragma unroll
        for (int kt = 0; kt < 4; ++kt) {
            bf16x8 aH, aL;
            const float* a8 = (const float*)&av[kt * 2];
#pragma unroll
            for (int i = 0; i < 8; ++i) {
                float x = a8[i];
                __bf16 hi = (__bf16)x;
                aH[i] = hi;
                aL[i] = (__bf16)(x - (float)hi);
            }
#pragma unroll
            for (int nt = 0; nt < 4; ++nt) {
                bf16x8 bh = hiTab[(kt * 4 + nt) * 64 + lane];
                bf16x8 bl = loTab[(kt * 4 + nt) * 64 + lane];
                acc[nt] = __builtin_amdgcn_mfma_f32_16x16x32_bf16(aH, bh, acc[nt], 0, 0, 0);
                acc[nt] = __builtin_amdgcn_mfma_f32_16x16x32_bf16(aL, bh, acc[nt], 0, 0, 0);
                acc[nt] = __builtin_amdgcn_mfma_f32_16x16x32_bf16(aH, bl, acc[nt], 0, 0, 0);
            }
        }

        // Lane holds z[row = g*4+j][col = nt*16+r] = acc[nt][j].
        // mag-partial = sum_col ssp(z+b1)*w2; reduce across the 16 lanes of group g.
        float s[4];
#pragma unroll
        for (int j = 0; j < 4; ++j) {
            float t = 0.0f;
#pragma unroll
            for (int nt = 0; nt < 4; ++nt) {
                float z = acc[nt][j] + b1v[nt];
                t += ssp_fast(z) * w2v[nt];
            }
            t += __shfl_xor(t, 1);
            t += __shfl_xor(t, 2);
            t += __shfl_xor(t, 4);
            t += __shfl_xor(t, 8);
            s[j] = t;
        }

        if (r < 4) {
            int e = e0 + g * 4 + r;
            if (e < E) {
                float mag = s[r] + b2v;
                mag_raw[e] = mag;
                int c = load_idx(eidx, is64, e);
                atomicAdd(&csum[c], mag);
                atomicAdd(&ccnt[c], 1.0f);
            }
        }
    }
}

// Kernel C: hash-join pairing (replaces argsort), debias, average, force scatter.
// The two directed copies of an undirected edge compute bitwise-identical keys
// (|(-v)/l| == |v/l| under IEEE), so an exact-match join reproduces the
// reference's sorted-pair grouping. Race-free: both partners walk the same
// probe sequence and slots never empty, so exactly one inserts.
__global__ __launch_bounds__(256) void pair_force_kernel(
    const float* __restrict__ vec,
    const float* __restrict__ len,
    const void* __restrict__ eidx,
    const float* __restrict__ mag_raw,
    const float* __restrict__ csum,
    const float* __restrict__ ccnt,
    unsigned long long* __restrict__ tab,
    float* __restrict__ out,
    const unsigned int* __restrict__ flag_any,
    int E, int hash_bits)
{
    int i = blockIdx.x * blockDim.x + threadIdx.x;
    if (i >= E) return;
    const int is64 = (flag_any[0] == 0u) ? 1 : 0;

    float l = len[i];
    float ux = vec[3 * i + 0] / l;
    float uy = vec[3 * i + 1] / l;
    float uz = vec[3 * i + 2] / l;
    float s3 = (fabsf(ux) + fabsf(uy)) + fabsf(uz);

    int ci_ = load_idx(eidx, is64, i);
    int ni_ = load_idx(eidx, is64, (long long)E + i);

    long long key = (long long)ci_ + (long long)ni_
                  + (long long)(1.0e10f * l)
                  + (long long)(1.0e10f * s3);

    unsigned long long entry = ((unsigned long long)key << IDX_BITS) | (unsigned)i;
    unsigned long long h = (unsigned long long)key * 0x9E3779B97F4A7C15ull;
    unsigned slot = (unsigned)(h >> (64 - hash_bits));
    const unsigned smask = (1u << hash_bits) - 1u;

    int j;
    while (true) {
        unsigned long long old = atomicCAS(&tab[slot], EMPTY_SLOT, entry);
        if (old == EMPTY_SLOT) return;  // first of the pair: partner finishes the job
        if ((old >> IDX_BITS) == (unsigned long long)key) {
            j = (int)(old & IDX_MASK);
            break;
        }
        slot = (slot + 1) & smask;
    }

    int cj_ = load_idx(eidx, is64, j);
    float mi = mag_raw[i] - csum[ci_] / fmaxf(ccnt[ci_], 1.0f);
    float mj = mag_raw[j] - csum[cj_] / fmaxf(ccnt[cj_], 1.0f);
    float avg = 0.5f * (mi + mj);

    atomicAdd(&out[ci_ * 3 + 0], avg * ux);
    atomicAdd(&out[ci_ * 3 + 1], avg * uy);
    atomicAdd(&out[ci_ * 3 + 2], avg * uz);

    float lj = len[j];
    float ujx = vec[3 * j + 0] / lj;
    float ujy = vec[3 * j + 1] / lj;
    float ujz = vec[3 * j + 2] / lj;
    atomicAdd(&out[cj_ * 3 + 0], avg * ujx);
    atomicAdd(&out[cj_ * 3 + 1], avg * ujy);
    atomicAdd(&out[cj_ * 3 + 2], avg * ujz);
}

extern "C" void kernel_launch(void* const* d_in, const int* in_sizes, int n_in,
                              void* d_out, int out_size, void* d_ws, size_t ws_size,
                              hipStream_t stream) {
    const float* feats = (const float*)d_in[0];
    const float* vec   = (const float*)d_in[1];
    const float* len   = (const float*)d_in[2];
    const void*  eidx  = d_in[3];
    const float* w1 = (const float*)d_in[4];
    const float* b1 = (const float*)d_in[5];
    const float* w2 = (const float*)d_in[6];
    const float* b2 = (const float*)d_in[7];
    float* out = (float*)d_out;

    const int E = in_sizes[0] / DFEAT;
    const int N = out_size / 3;

    // Workspace layout (256B aligned regions):
    //   mag_raw: E floats | csum: N floats | ccnt: N floats | flag: 256B | tab
    char* ws = (char*)d_ws;
    size_t off_mag  = 0;
    size_t off_csum = (off_mag + (size_t)E * 4 + 255) & ~(size_t)255;
    size_t off_ccnt = off_csum + (size_t)N * 4;
    size_t off_flag = (off_ccnt + (size_t)N * 4 + 255) & ~(size_t)255;
    size_t off_tab  = off_flag + 256;

    float* mag_raw = (float*)(ws + off_mag);
    float* csum    = (float*)(ws + off_csum);
    float* ccnt    = (float*)(ws + off_ccnt);
    unsigned int* flag_any = (unsigned int*)(ws + off_flag);

    int hash_bits = 21;
    while (hash_bits > 19 && off_tab + (8ull << hash_bits) > ws_size) --hash_bits;
    unsigned long long* tab = (unsigned long long*)(ws + off_tab);

    hipMemsetAsync(csum, 0, (size_t)2 * N * 4, stream);
    hipMemsetAsync(flag_any, 0, 256, stream);
    hipMemsetAsync(tab, 0xFF, (size_t)8 << hash_bits, stream);
    hipMemsetAsync(out, 0, (size_t)out_size * 4, stream);

    int n_check = E < 1024 ? E : 1024;
    detect_idx_kernel<<<1, 256, 0, stream>>>((const unsigned int*)eidx, n_check, flag_any);

    mlp_mag_kernel<<<2048, 256, 0, stream>>>(feats, eidx, w1, b1, w2, b2,
                                             mag_raw, csum, ccnt, flag_any, E);

    int blocks = (E + 255) / 256;
    pair_force_kernel<<<blocks, 256, 0, stream>>>(vec, len, eidx, mag_raw, csum, ccnt,
                                                  tab, out, flag_any, E, hash_bits);
}

// Round 4
// 775.179 us; speedup vs baseline: 1.2892x; 1.2892x over previous
//
#include <hip/hip_runtime.h>

typedef __bf16 bf16x8 __attribute__((ext_vector_type(8)));
typedef float f32x4 __attribute__((ext_vector_type(4)));

#define DFEAT 128
#define HDIM 64
#define IDX_BITS 21
#define IDX_MASK ((1u << IDX_BITS) - 1)
#define EMPTY_SLOT 0xFFFFFFFFFFFFFFFFull

// fast shifted-softplus: log(1+e^x) - log2, via native v_exp_f32/v_log_f32
__device__ __forceinline__ float ssp_fast(float x) {
    float m = fmaxf(x, 0.0f);
    float t = __expf(-fabsf(x));
    return m + __logf(1.0f + t) - 0.69314718055994531f;
}

// edge_index may arrive as int32 (harness contract) or int64 (reference dtype).
// Detect at runtime: int64 layout has all-zero odd dwords (values < 2^31).
__global__ void detect_idx_kernel(const unsigned int* __restrict__ p, int n_check,
                                  unsigned int* __restrict__ flag_any) {
    unsigned int acc = 0;
    for (int i = threadIdx.x; i < n_check; i += blockDim.x)
        acc |= p[2 * i + 1];
    if (acc) atomicOr(flag_any, 1u);
}

__device__ __forceinline__ int load_idx(const void* p, int is64, long long i) {
    if (is64) return (int)((const long long*)p)[i];
    return ((const int*)p)[i];
}

__device__ __forceinline__ void load_tile(float4 (&av)[8], const float* __restrict__ feats,
                                          int e0, int r, int g, int E) {
    int erow = e0 + r;
    if (erow < E) {
        const float4* fp = (const float4*)(feats + (size_t)erow * DFEAT);
#pragma unroll
        for (int kt = 0; kt < 4; ++kt) {
            av[kt * 2 + 0] = fp[kt * 8 + g * 2 + 0];
            av[kt * 2 + 1] = fp[kt * 8 + g * 2 + 1];
        }
    } else {
#pragma unroll
        for (int q = 0; q < 8; ++q) av[q] = make_float4(0.f, 0.f, 0.f, 0.f);
    }
}

__device__ __forceinline__ void compute_store(const float4 (&av)[8],
                                              const bf16x8* __restrict__ hiTab,
                                              const bf16x8* __restrict__ loTab,
                                              const float (&b1v)[4], const float (&w2v)[4],
                                              float b2v, float* __restrict__ mag_raw,
                                              int e0, int lane, int r, int g, int E) {
    f32x4 acc[4] = {{0.f,0.f,0.f,0.f},{0.f,0.f,0.f,0.f},{0.f,0.f,0.f,0.f},{0.f,0.f,0.f,0.f}};
#pragma unroll
    for (int kt = 0; kt < 4; ++kt) {
        bf16x8 aH, aL;
        const float* a8 = (const float*)&av[kt * 2];
#pragma unroll
        for (int i = 0; i < 8; ++i) {
            float x = a8[i];
            __bf16 hi = (__bf16)x;
            aH[i] = hi;
            aL[i] = (__bf16)(x - (float)hi);
        }
#pragma unroll
        for (int nt = 0; nt < 4; ++nt) {
            bf16x8 bh = hiTab[(kt * 4 + nt) * 64 + lane];
            bf16x8 bl = loTab[(kt * 4 + nt) * 64 + lane];
            acc[nt] = __builtin_amdgcn_mfma_f32_16x16x32_bf16(aH, bh, acc[nt], 0, 0, 0);
            acc[nt] = __builtin_amdgcn_mfma_f32_16x16x32_bf16(aL, bh, acc[nt], 0, 0, 0);
            acc[nt] = __builtin_amdgcn_mfma_f32_16x16x32_bf16(aH, bl, acc[nt], 0, 0, 0);
        }
    }
    // Lane holds z[row=g*4+j][col=nt*16+r] = acc[nt][j].
    float s[4];
#pragma unroll
    for (int j = 0; j < 4; ++j) {
        float t = 0.0f;
#pragma unroll
        for (int nt = 0; nt < 4; ++nt) {
            float z = acc[nt][j] + b1v[nt];
            t += ssp_fast(z) * w2v[nt];
        }
        t += __shfl_xor(t, 1);
        t += __shfl_xor(t, 2);
        t += __shfl_xor(t, 4);
        t += __shfl_xor(t, 8);
        s[j] = t;
    }
    if (r < 4) {
        int e = e0 + g * 4 + r;
        if (e < E) mag_raw[e] = s[r] + b2v;
    }
}

// Kernel A: per-edge MLP via split-bf16 MFMA (Ah*Wh + Al*Wh + Ah*Wl). No atomics —
// pure streaming GEMM with ping-pong double-buffered feature tiles.
__global__ __launch_bounds__(256, 4) void mlp_mag_kernel(
    const float* __restrict__ feats,
    const float* __restrict__ w1,
    const float* __restrict__ b1,
    const float* __restrict__ w2,
    const float* __restrict__ b2,
    float* __restrict__ mag_raw,
    int E)
{
    __shared__ __align__(16) unsigned char smem[32768];
    float* w1s = (float*)smem;                 // transient: raw w1 (32 KB)
    bf16x8* hiTab = (bf16x8*)smem;             // final: hi frags (16 KB)
    bf16x8* loTab = (bf16x8*)(smem + 16384);   // final: lo frags (16 KB)

    const int lane = threadIdx.x & 63;
    const int r = lane & 15;
    const int g = lane >> 4;
    const int wave = blockIdx.x * (blockDim.x >> 6) + (threadIdx.x >> 6);
    const int nwaves = gridDim.x * (blockDim.x >> 6);

    // Stage B fragment tables in LDS (once per block).
    for (int idx = threadIdx.x; idx < DFEAT * HDIM / 4; idx += blockDim.x)
        ((float4*)w1s)[idx] = ((const float4*)w1)[idx];
    __syncthreads();
    {
        const int tkt = threadIdx.x >> 6;
        const int tl = threadIdx.x & 63;
        const int tg = tl >> 4, tr = tl & 15;
        float vals[4][8];
#pragma unroll
        for (int nt = 0; nt < 4; ++nt)
#pragma unroll
            for (int i = 0; i < 8; ++i)
                vals[nt][i] = w1s[(tkt * 32 + tg * 8 + i) * HDIM + nt * 16 + tr];
        __syncthreads();
#pragma unroll
        for (int nt = 0; nt < 4; ++nt) {
            bf16x8 h, lo;
#pragma unroll
            for (int i = 0; i < 8; ++i) {
                float w = vals[nt][i];
                __bf16 hi = (__bf16)w;
                h[i] = hi;
                lo[i] = (__bf16)(w - (float)hi);
            }
            hiTab[(tkt * 4 + nt) * 64 + tl] = h;
            loTab[(tkt * 4 + nt) * 64 + tl] = lo;
        }
        __syncthreads();
    }

    float b1v[4], w2v[4];
#pragma unroll
    for (int nt = 0; nt < 4; ++nt) {
        b1v[nt] = b1[nt * 16 + r];
        w2v[nt] = w2[nt * 16 + r];
    }
    const float b2v = b2[0];

    const int ntiles = (E + 15) >> 4;
    float4 A0[8], A1[8];
    int t = wave;
    bool have = t < ntiles;
    if (have) load_tile(A0, feats, t << 4, r, g, E);
    while (have) {
        int tn = t + nwaves;
        bool haven = tn < ntiles;
        if (haven) load_tile(A1, feats, tn << 4, r, g, E);
        compute_store(A0, hiTab, loTab, b1v, w2v, b2v, mag_raw, t << 4, lane, r, g, E);
        t = tn; have = haven;
        if (!have) break;
        tn = t + nwaves;
        haven = tn < ntiles;
        if (haven) load_tile(A0, feats, tn << 4, r, g, E);
        compute_store(A1, hiTab, loTab, b1v, w2v, b2v, mag_raw, t << 4, lane, r, g, E);
        t = tn; have = haven;
    }
}

// Kernel B: scatter-mean inputs via sorted-run segmented reduction.
// ~2 atomics per center-run instead of 2 per edge; correct even if unsorted.
__global__ __launch_bounds__(256) void bias_kernel(
    const void* __restrict__ eidx,
    const float* __restrict__ mag,
    float* __restrict__ csum,
    float* __restrict__ ccnt,
    const unsigned int* __restrict__ flag_any,
    int E)
{
    __shared__ int cs[256];
    __shared__ float ms[256];
    const int is64 = (flag_any[0] == 0u) ? 1 : 0;
    const int tloc = threadIdx.x;
    const int i = blockIdx.x * 256 + tloc;
    int c = -1; float m = 0.0f;
    if (i < E) { c = load_idx(eidx, is64, i); m = mag[i]; }
    cs[tloc] = c; ms[tloc] = m;
    __syncthreads();
    if (i < E) {
        bool leader = (tloc == 0) || (cs[tloc - 1] != c);
        if (leader) {
            float s = 0.0f; int n = 0; int j = tloc;
            int lim = min(256, E - blockIdx.x * 256);
            while (j < lim && cs[j] == c) { s += ms[j]; ++n; ++j; }
            atomicAdd(&csum[c], s);
            atomicAdd(&ccnt[c], (float)n);
        }
    }
}

// Kernel C: hash-join pairing (replaces argsort). The two directed copies of an
// undirected edge compute bitwise-identical keys (|(-v)/l| == |v/l| under IEEE),
// so an exact-match join reproduces the reference's sorted-pair grouping.
// Finisher debiases both, averages, and writes the avg IN PLACE into mag
// (each edge's slot is touched only by its own pair's finisher).
__global__ __launch_bounds__(256) void pair_kernel(
    const float* __restrict__ vec,
    const float* __restrict__ len,
    const void* __restrict__ eidx,
    float* __restrict__ mag,
    const float* __restrict__ csum,
    const float* __restrict__ ccnt,
    unsigned long long* __restrict__ tab,
    const unsigned int* __restrict__ flag_any,
    int E, int hash_bits)
{
    int i = blockIdx.x * blockDim.x + threadIdx.x;
    if (i >= E) return;
    const int is64 = (flag_any[0] == 0u) ? 1 : 0;

    float l = len[i];
    float ux = vec[3 * i + 0] / l;
    float uy = vec[3 * i + 1] / l;
    float uz = vec[3 * i + 2] / l;
    float s3 = (fabsf(ux) + fabsf(uy)) + fabsf(uz);

    int ci_ = load_idx(eidx, is64, i);
    int ni_ = load_idx(eidx, is64, (long long)E + i);

    long long key = (long long)ci_ + (long long)ni_
                  + (long long)(1.0e10f * l)
                  + (long long)(1.0e10f * s3);

    unsigned long long entry = ((unsigned long long)key << IDX_BITS) | (unsigned)i;
    unsigned long long h = (unsigned long long)key * 0x9E3779B97F4A7C15ull;
    unsigned slot = (unsigned)(h >> (64 - hash_bits));
    const unsigned smask = (1u << hash_bits) - 1u;

    int j;
    while (true) {
        unsigned long long old = atomicCAS(&tab[slot], EMPTY_SLOT, entry);
        if (old == EMPTY_SLOT) return;  // first arrival: partner finishes the job
        if ((old >> IDX_BITS) == (unsigned long long)key) {
            j = (int)(old & IDX_MASK);
            break;
        }
        slot = (slot + 1) & smask;
    }

    int cj_ = load_idx(eidx, is64, j);
    float mi = mag[i] - csum[ci_] / fmaxf(ccnt[ci_], 1.0f);
    float mj = mag[j] - csum[cj_] / fmaxf(ccnt[cj_], 1.0f);
    float avg = 0.5f * (mi + mj);
    mag[i] = avg;
    mag[j] = avg;
}

// Kernel D: edge_force = mag*unit, segment-sum by (sorted) center via run
// detection; ~3 atomics per run instead of 3 per edge. Correct if unsorted.
__global__ __launch_bounds__(256) void force_kernel(
    const float* __restrict__ vec,
    const float* __restrict__ len,
    const void* __restrict__ eidx,
    const float* __restrict__ mag,
    float* __restrict__ out,
    const unsigned int* __restrict__ flag_any,
    int E)
{
    __shared__ int cs[256];
    __shared__ float fx[256], fy[256], fz[256];
    const int is64 = (flag_any[0] == 0u) ? 1 : 0;
    const int tloc = threadIdx.x;
    const int i = blockIdx.x * 256 + tloc;
    int c = -1;
    if (i < E) {
        c = load_idx(eidx, is64, i);
        float l = len[i];
        float m = mag[i];
        fx[tloc] = m * vec[3 * i + 0] / l;
        fy[tloc] = m * vec[3 * i + 1] / l;
        fz[tloc] = m * vec[3 * i + 2] / l;
    }
    cs[tloc] = c;
    __syncthreads();
    if (i < E) {
        bool leader = (tloc == 0) || (cs[tloc - 1] != c);
        if (leader) {
            float sx = 0.f, sy = 0.f, sz = 0.f;
            int j = tloc;
            int lim = min(256, E - blockIdx.x * 256);
            while (j < lim && cs[j] == c) { sx += fx[j]; sy += fy[j]; sz += fz[j]; ++j; }
            atomicAdd(&out[c * 3 + 0], sx);
            atomicAdd(&out[c * 3 + 1], sy);
            atomicAdd(&out[c * 3 + 2], sz);
        }
    }
}

extern "C" void kernel_launch(void* const* d_in, const int* in_sizes, int n_in,
                              void* d_out, int out_size, void* d_ws, size_t ws_size,
                              hipStream_t stream) {
    const float* feats = (const float*)d_in[0];
    const float* vec   = (const float*)d_in[1];
    const float* len   = (const float*)d_in[2];
    const void*  eidx  = d_in[3];
    const float* w1 = (const float*)d_in[4];
    const float* b1 = (const float*)d_in[5];
    const float* w2 = (const float*)d_in[6];
    const float* b2 = (const float*)d_in[7];
    float* out = (float*)d_out;

    const int E = in_sizes[0] / DFEAT;
    const int N = out_size / 3;

    // Workspace: mag (E f32) | csum (N) | ccnt (N) | flag (256B) | tab
    char* ws = (char*)d_ws;
    size_t off_mag  = 0;
    size_t off_csum = (off_mag + (size_t)E * 4 + 255) & ~(size_t)255;
    size_t off_ccnt = off_csum + (size_t)N * 4;
    size_t off_flag = (off_ccnt + (size_t)N * 4 + 255) & ~(size_t)255;
    size_t off_tab  = off_flag + 256;

    float* mag     = (float*)(ws + off_mag);
    float* csum    = (float*)(ws + off_csum);
    float* ccnt    = (float*)(ws + off_ccnt);
    unsigned int* flag_any = (unsigned int*)(ws + off_flag);

    int hash_bits = 21;
    while (hash_bits > 20 && off_tab + (8ull << hash_bits) > ws_size) --hash_bits;
    unsigned long long* tab = (unsigned long long*)(ws + off_tab);

    hipMemsetAsync(csum, 0, (size_t)2 * N * 4, stream);
    hipMemsetAsync(flag_any, 0, 256, stream);
    hipMemsetAsync(tab, 0xFF, (size_t)8 << hash_bits, stream);
    hipMemsetAsync(out, 0, (size_t)out_size * 4, stream);

    int n_check = E < 1024 ? E : 1024;
    detect_idx_kernel<<<1, 256, 0, stream>>>((const unsigned int*)eidx, n_check, flag_any);

    mlp_mag_kernel<<<1024, 256, 0, stream>>>(feats, w1, b1, w2, b2, mag, E);

    int eblocks = (E + 255) / 256;
    bias_kernel<<<eblocks, 256, 0, stream>>>(eidx, mag, csum, ccnt, flag_any, E);
    pair_kernel<<<eblocks, 256, 0, stream>>>(vec, len, eidx, mag, csum, ccnt,
                                             tab, flag_any, E, hash_bits);
    force_kernel<<<eblocks, 256, 0, stream>>>(vec, len, eidx, mag, out, flag_any, E);
}

// Round 5
// 572.524 us; speedup vs baseline: 1.7455x; 1.3540x over previous
//
#include <hip/hip_runtime.h>

typedef __bf16 bf16x8 __attribute__((ext_vector_type(8)));
typedef float f32x4 __attribute__((ext_vector_type(4)));

#define DFEAT 128
#define HDIM 64
#define IDX_BITS 21
#define IDX_MASK ((1u << IDX_BITS) - 1)
#define EMPTY_SLOT 0xFFFFFFFFFFFFFFFFull

// fast shifted-softplus: log(1+e^x) - log2, via native v_exp_f32/v_log_f32
__device__ __forceinline__ float ssp_fast(float x) {
    float m = fmaxf(x, 0.0f);
    float t = __expf(-fabsf(x));
    return m + __logf(1.0f + t) - 0.69314718055994531f;
}

// edge_index may arrive as int32 (harness contract) or int64 (reference dtype).
// Detect at runtime: int64 layout has all-zero odd dwords (values < 2^31).
__global__ void detect_idx_kernel(const unsigned int* __restrict__ p, int n_check,
                                  unsigned int* __restrict__ flag_any) {
    unsigned int acc = 0;
    for (int i = threadIdx.x; i < n_check; i += blockDim.x)
        acc |= p[2 * i + 1];
    if (acc) atomicOr(flag_any, 1u);
}

__device__ __forceinline__ int load_idx(const void* p, int is64, long long i) {
    if (is64) return (int)((const long long*)p)[i];
    return ((const int*)p)[i];
}

// hi/lo bf16 split of 8 floats from two float4s — member access only, no casts.
#define CVT8(P, Q, H, L) do { \
    H[0] = (__bf16)P.x; L[0] = (__bf16)(P.x - (float)H[0]); \
    H[1] = (__bf16)P.y; L[1] = (__bf16)(P.y - (float)H[1]); \
    H[2] = (__bf16)P.z; L[2] = (__bf16)(P.z - (float)H[2]); \
    H[3] = (__bf16)P.w; L[3] = (__bf16)(P.w - (float)H[3]); \
    H[4] = (__bf16)Q.x; L[4] = (__bf16)(Q.x - (float)H[4]); \
    H[5] = (__bf16)Q.y; L[5] = (__bf16)(Q.y - (float)H[5]); \
    H[6] = (__bf16)Q.z; L[6] = (__bf16)(Q.z - (float)H[6]); \
    H[7] = (__bf16)Q.w; L[7] = (__bf16)(Q.w - (float)H[7]); \
} while (0)

#define MF(A, B, C) __builtin_amdgcn_mfma_f32_16x16x32_bf16(A, B, C, 0, 0, 0)

// One K-chunk (32 of 128): split A to hi/lo, 3-MFMA split product into 4 N-tiles.
#define KSTEP(P, Q, KT) do { \
    bf16x8 h, l, bh, bl; \
    CVT8(P, Q, h, l); \
    bh = hiTab[((KT)*4 + 0) * 64 + lane]; bl = loTab[((KT)*4 + 0) * 64 + lane]; \
    acc0 = MF(h, bh, acc0); acc0 = MF(l, bh, acc0); acc0 = MF(h, bl, acc0); \
    bh = hiTab[((KT)*4 + 1) * 64 + lane]; bl = loTab[((KT)*4 + 1) * 64 + lane]; \
    acc1 = MF(h, bh, acc1); acc1 = MF(l, bh, acc1); acc1 = MF(h, bl, acc1); \
    bh = hiTab[((KT)*4 + 2) * 64 + lane]; bl = loTab[((KT)*4 + 2) * 64 + lane]; \
    acc2 = MF(h, bh, acc2); acc2 = MF(l, bh, acc2); acc2 = MF(h, bl, acc2); \
    bh = hiTab[((KT)*4 + 3) * 64 + lane]; bl = loTab[((KT)*4 + 3) * 64 + lane]; \
    acc3 = MF(h, bh, acc3); acc3 = MF(l, bh, acc3); acc3 = MF(h, bl, acc3); \
} while (0)

// row-slice ssp + w2 dot + 16-lane reduce for C-row j (compile-time J).
#define REDJ(J, OUT) do { \
    float z0 = acc0[J] + b1v0, z1 = acc1[J] + b1v1; \
    float z2 = acc2[J] + b1v2, z3 = acc3[J] + b1v3; \
    float t = ssp_fast(z0) * w2v0 + ssp_fast(z1) * w2v1 \
            + ssp_fast(z2) * w2v2 + ssp_fast(z3) * w2v3; \
    t += __shfl_xor(t, 1); t += __shfl_xor(t, 2); \
    t += __shfl_xor(t, 4); t += __shfl_xor(t, 8); \
    OUT = t; \
} while (0)

// Kernel A: per-edge MLP via split-bf16 MFMA (Ah*Wh + Al*Wh + Ah*Wl).
// All per-tile state in NAMED registers (no runtime-indexed locals, no pointer
// casts) — rounds 2-4 leaked ~200 MB/pass of scratch through s[r] and
// (float*)&av[] (rule #20), which was the real 630-us limiter.
__global__ __launch_bounds__(256, 4) void mlp_mag_kernel(
    const float* __restrict__ feats,
    const float* __restrict__ w1,
    const float* __restrict__ b1,
    const float* __restrict__ w2,
    const float* __restrict__ b2,
    float* __restrict__ mag_raw,
    int E)
{
    __shared__ __align__(16) unsigned char smem[32768];
    float* w1s = (float*)smem;                 // transient: raw w1 (32 KB)
    bf16x8* hiTab = (bf16x8*)smem;             // final: hi frags (16 KB)
    bf16x8* loTab = (bf16x8*)(smem + 16384);   // final: lo frags (16 KB)

    const int lane = threadIdx.x & 63;
    const int r = lane & 15;
    const int g = lane >> 4;
    const int wave = blockIdx.x * (blockDim.x >> 6) + (threadIdx.x >> 6);
    const int nwaves = gridDim.x * (blockDim.x >> 6);

    // Stage B fragment tables in LDS (once per block).
    for (int idx = threadIdx.x; idx < DFEAT * HDIM / 4; idx += blockDim.x)
        ((float4*)w1s)[idx] = ((const float4*)w1)[idx];
    __syncthreads();
    {
        const int tkt = threadIdx.x >> 6;
        const int tl = threadIdx.x & 63;
        const int tg = tl >> 4, tr = tl & 15;
        float vals[4][8];
#pragma unroll
        for (int nt = 0; nt < 4; ++nt)
#pragma unroll
            for (int i = 0; i < 8; ++i)
                vals[nt][i] = w1s[(tkt * 32 + tg * 8 + i) * HDIM + nt * 16 + tr];
        __syncthreads();
#pragma unroll
        for (int nt = 0; nt < 4; ++nt) {
            bf16x8 h, lo;
#pragma unroll
            for (int i = 0; i < 8; ++i) {
                float w = vals[nt][i];
                __bf16 hi = (__bf16)w;
                h[i] = hi;
                lo[i] = (__bf16)(w - (float)hi);
            }
            hiTab[(tkt * 4 + nt) * 64 + tl] = h;
            loTab[(tkt * 4 + nt) * 64 + tl] = lo;
        }
        __syncthreads();
    }

    const float b1v0 = b1[0 * 16 + r], b1v1 = b1[1 * 16 + r];
    const float b1v2 = b1[2 * 16 + r], b1v3 = b1[3 * 16 + r];
    const float w2v0 = w2[0 * 16 + r], w2v1 = w2[1 * 16 + r];
    const float w2v2 = w2[2 * 16 + r], w2v3 = w2[3 * 16 + r];
    const float b2v = b2[0];

    const int ntiles = (E + 15) >> 4;
    for (int tile = wave; tile < ntiles; tile += nwaves) {
        const int e0 = tile << 4;
        int er = e0 + r;
        if (er >= E) er = E - 1;           // clamp: loads stay valid; store is guarded

        const float4* fp = (const float4*)(feats + (size_t)er * DFEAT) + g * 2;
        float4 p0 = fp[0],  p1 = fp[1];
        float4 p2 = fp[8],  p3 = fp[9];
        float4 p4 = fp[16], p5 = fp[17];
        float4 p6 = fp[24], p7 = fp[25];

        f32x4 acc0 = {0.f,0.f,0.f,0.f}, acc1 = {0.f,0.f,0.f,0.f};
        f32x4 acc2 = {0.f,0.f,0.f,0.f}, acc3 = {0.f,0.f,0.f,0.f};
        KSTEP(p0, p1, 0);
        KSTEP(p2, p3, 1);
        KSTEP(p4, p5, 2);
        KSTEP(p6, p7, 3);

        float s0, s1, s2, s3;
        REDJ(0, s0); REDJ(1, s1); REDJ(2, s2); REDJ(3, s3);

        if (r < 4) {
            int e = e0 + g * 4 + r;
            if (e < E) {
                // 4-way select by r without a runtime-indexed array (cndmask chain)
                float sel = (r == 0) ? s0 : (r == 1) ? s1 : (r == 2) ? s2 : s3;
                mag_raw[e] = sel + b2v;
            }
        }
    }
}

// Kernel B: scatter-mean inputs via sorted-run segmented reduction.
// ~2 atomics per center-run instead of 2 per edge; correct even if unsorted.
__global__ __launch_bounds__(256) void bias_kernel(
    const void* __restrict__ eidx,
    const float* __restrict__ mag,
    float* __restrict__ csum,
    float* __restrict__ ccnt,
    const unsigned int* __restrict__ flag_any,
    int E)
{
    __shared__ int cs[256];
    __shared__ float ms[256];
    const int is64 = (flag_any[0] == 0u) ? 1 : 0;
    const int tloc = threadIdx.x;
    const int i = blockIdx.x * 256 + tloc;
    int c = -1; float m = 0.0f;
    if (i < E) { c = load_idx(eidx, is64, i); m = mag[i]; }
    cs[tloc] = c; ms[tloc] = m;
    __syncthreads();
    if (i < E) {
        bool leader = (tloc == 0) || (cs[tloc - 1] != c);
        if (leader) {
            float s = 0.0f; int n = 0; int j = tloc;
            int lim = min(256, E - blockIdx.x * 256);
            while (j < lim && cs[j] == c) { s += ms[j]; ++n; ++j; }
            atomicAdd(&csum[c], s);
            atomicAdd(&ccnt[c], (float)n);
        }
    }
}

// Kernel C: hash-join pairing (replaces argsort). The two directed copies of an
// undirected edge compute bitwise-identical keys (|(-v)/l| == |v/l| under IEEE),
// so an exact-match join reproduces the reference's sorted-pair grouping.
// Finisher debiases both, averages, and writes the avg IN PLACE into mag
// (each edge's slot is touched only by its own pair's finisher).
__global__ __launch_bounds__(256) void pair_kernel(
    const float* __restrict__ vec,
    const float* __restrict__ len,
    const void* __restrict__ eidx,
    float* __restrict__ mag,
    const float* __restrict__ csum,
    const float* __restrict__ ccnt,
    unsigned long long* __restrict__ tab,
    const unsigned int* __restrict__ flag_any,
    int E, int hash_bits)
{
    int i = blockIdx.x * blockDim.x + threadIdx.x;
    if (i >= E) return;
    const int is64 = (flag_any[0] == 0u) ? 1 : 0;

    float l = len[i];
    float ux = vec[3 * i + 0] / l;
    float uy = vec[3 * i + 1] / l;
    float uz = vec[3 * i + 2] / l;
    float s3 = (fabsf(ux) + fabsf(uy)) + fabsf(uz);

    int ci_ = load_idx(eidx, is64, i);
    int ni_ = load_idx(eidx, is64, (long long)E + i);

    long long key = (long long)ci_ + (long long)ni_
                  + (long long)(1.0e10f * l)
                  + (long long)(1.0e10f * s3);

    unsigned long long entry = ((unsigned long long)key << IDX_BITS) | (unsigned)i;
    unsigned long long h = (unsigned long long)key * 0x9E3779B97F4A7C15ull;
    unsigned slot = (unsigned)(h >> (64 - hash_bits));
    const unsigned smask = (1u << hash_bits) - 1u;

    int j;
    while (true) {
        unsigned long long old = atomicCAS(&tab[slot], EMPTY_SLOT, entry);
        if (old == EMPTY_SLOT) return;  // first arrival: partner finishes the job
        if ((old >> IDX_BITS) == (unsigned long long)key) {
            j = (int)(old & IDX_MASK);
            break;
        }
        slot = (slot + 1) & smask;
    }

    int cj_ = load_idx(eidx, is64, j);
    float mi = mag[i] - csum[ci_] / fmaxf(ccnt[ci_], 1.0f);
    float mj = mag[j] - csum[cj_] / fmaxf(ccnt[cj_], 1.0f);
    float avg = 0.5f * (mi + mj);
    mag[i] = avg;
    mag[j] = avg;
}

// Kernel D: edge_force = mag*unit, segment-sum by (sorted) center via run
// detection; ~3 atomics per run instead of 3 per edge. Correct if unsorted.
__global__ __launch_bounds__(256) void force_kernel(
    const float* __restrict__ vec,
    const float* __restrict__ len,
    const void* __restrict__ eidx,
    const float* __restrict__ mag,
    float* __restrict__ out,
    const unsigned int* __restrict__ flag_any,
    int E)
{
    __shared__ int cs[256];
    __shared__ float fx[256], fy[256], fz[256];
    const int is64 = (flag_any[0] == 0u) ? 1 : 0;
    const int tloc = threadIdx.x;
    const int i = blockIdx.x * 256 + tloc;
    int c = -1;
    if (i < E) {
        c = load_idx(eidx, is64, i);
        float l = len[i];
        float m = mag[i];
        fx[tloc] = m * vec[3 * i + 0] / l;
        fy[tloc] = m * vec[3 * i + 1] / l;
        fz[tloc] = m * vec[3 * i + 2] / l;
    }
    cs[tloc] = c;
    __syncthreads();
    if (i < E) {
        bool leader = (tloc == 0) || (cs[tloc - 1] != c);
        if (leader) {
            float sx = 0.f, sy = 0.f, sz = 0.f;
            int j = tloc;
            int lim = min(256, E - blockIdx.x * 256);
            while (j < lim && cs[j] == c) { sx += fx[j]; sy += fy[j]; sz += fz[j]; ++j; }
            atomicAdd(&out[c * 3 + 0], sx);
            atomicAdd(&out[c * 3 + 1], sy);
            atomicAdd(&out[c * 3 + 2], sz);
        }
    }
}

extern "C" void kernel_launch(void* const* d_in, const int* in_sizes, int n_in,
                              void* d_out, int out_size, void* d_ws, size_t ws_size,
                              hipStream_t stream) {
    const float* feats = (const float*)d_in[0];
    const float* vec   = (const float*)d_in[1];
    const float* len   = (const float*)d_in[2];
    const void*  eidx  = d_in[3];
    const float* w1 = (const float*)d_in[4];
    const float* b1 = (const float*)d_in[5];
    const float* w2 = (const float*)d_in[6];
    const float* b2 = (const float*)d_in[7];
    float* out = (float*)d_out;

    const int E = in_sizes[0] / DFEAT;
    const int N = out_size / 3;

    // Workspace: mag (E f32) | csum (N) | ccnt (N) | flag (256B) | tab
    char* ws = (char*)d_ws;
    size_t off_mag  = 0;
    size_t off_csum = (off_mag + (size_t)E * 4 + 255) & ~(size_t)255;
    size_t off_ccnt = off_csum + (size_t)N * 4;
    size_t off_flag = (off_ccnt + (size_t)N * 4 + 255) & ~(size_t)255;
    size_t off_tab  = off_flag + 256;

    float* mag     = (float*)(ws + off_mag);
    float* csum    = (float*)(ws + off_csum);
    float* ccnt    = (float*)(ws + off_ccnt);
    unsigned int* flag_any = (unsigned int*)(ws + off_flag);

    int hash_bits = 21;
    while (hash_bits > 20 && off_tab + (8ull << hash_bits) > ws_size) --hash_bits;
    unsigned long long* tab = (unsigned long long*)(ws + off_tab);

    hipMemsetAsync(csum, 0, (size_t)2 * N * 4, stream);
    hipMemsetAsync(flag_any, 0, 256, stream);
    hipMemsetAsync(tab, 0xFF, (size_t)8 << hash_bits, stream);
    hipMemsetAsync(out, 0, (size_t)out_size * 4, stream);

    int n_check = E < 1024 ? E : 1024;
    detect_idx_kernel<<<1, 256, 0, stream>>>((const unsigned int*)eidx, n_check, flag_any);

    mlp_mag_kernel<<<1024, 256, 0, stream>>>(feats, w1, b1, w2, b2, mag, E);

    int eblocks = (E + 255) / 256;
    bias_kernel<<<eblocks, 256, 0, stream>>>(eidx, mag, csum, ccnt, flag_any, E);
    pair_kernel<<<eblocks, 256, 0, stream>>>(vec, len, eidx, mag, csum, ccnt,
                                             tab, flag_any, E, hash_bits);
    force_kernel<<<eblocks, 256, 0, stream>>>(vec, len, eidx, mag, out, flag_any, E);
}

// Round 6
// 335.353 us; speedup vs baseline: 2.9799x; 1.7072x over previous
//
#include <hip/hip_runtime.h>

typedef __bf16 bf16x8 __attribute__((ext_vector_type(8)));
typedef float f32x4 __attribute__((ext_vector_type(4)));

#define DFEAT 128
#define HDIM 64
#define IDX_BITS 21
#define IDX_MASK ((1u << IDX_BITS) - 1)
#define EMPTY_SLOT 0xFFFFFFFFFFFFFFFFull

// fast shifted-softplus: log(1+e^x) - log2, via native v_exp_f32/v_log_f32
__device__ __forceinline__ float ssp_fast(float x) {
    float m = fmaxf(x, 0.0f);
    float t = __expf(-fabsf(x));
    return m + __logf(1.0f + t) - 0.69314718055994531f;
}

// edge_index may arrive as int32 (harness contract) or int64 (reference dtype).
// Detect at runtime: int64 layout has all-zero odd dwords (values < 2^31).
__global__ void detect_idx_kernel(const unsigned int* __restrict__ p, int n_check,
                                  unsigned int* __restrict__ flag_any) {
    unsigned int acc = 0;
    for (int i = threadIdx.x; i < n_check; i += blockDim.x)
        acc |= p[2 * i + 1];
    if (acc) atomicOr(flag_any, 1u);
}

__device__ __forceinline__ int load_idx(const void* p, int is64, long long i) {
    if (is64) return (int)((const long long*)p)[i];
    return ((const int*)p)[i];
}

// bf16 convert of 8 floats from two float4s — member access only, no casts.
#define CVT8H(P, Q, H) do { \
    H[0] = (__bf16)P.x; H[1] = (__bf16)P.y; H[2] = (__bf16)P.z; H[3] = (__bf16)P.w; \
    H[4] = (__bf16)Q.x; H[5] = (__bf16)Q.y; H[6] = (__bf16)Q.z; H[7] = (__bf16)Q.w; \
} while (0)

#define MF(A, B, C) __builtin_amdgcn_mfma_f32_16x16x32_bf16(A, B, C, 0, 0, 0)

// One K-chunk (32 of 128): convert A, 1 MFMA per N-tile (pure bf16 —
// error budget: delta-z sigma ~0.003, force absmax ~0.03 << 0.1406 threshold;
// the round-2..5 hi/lo split cost ~2x VALU and kept the kernel VALU-bound).
#define KSTEP(P, Q, KT) do { \
    bf16x8 h, bh; \
    CVT8H(P, Q, h); \
    bh = hiTab[((KT)*4 + 0) * 64 + lane]; acc0 = MF(h, bh, acc0); \
    bh = hiTab[((KT)*4 + 1) * 64 + lane]; acc1 = MF(h, bh, acc1); \
    bh = hiTab[((KT)*4 + 2) * 64 + lane]; acc2 = MF(h, bh, acc2); \
    bh = hiTab[((KT)*4 + 3) * 64 + lane]; acc3 = MF(h, bh, acc3); \
} while (0)

// row-slice ssp + w2 dot + 16-lane reduce for C-row j (compile-time J).
#define REDJ(J, OUT) do { \
    float z0 = acc0[J] + b1v0, z1 = acc1[J] + b1v1; \
    float z2 = acc2[J] + b1v2, z3 = acc3[J] + b1v3; \
    float t = ssp_fast(z0) * w2v0 + ssp_fast(z1) * w2v1 \
            + ssp_fast(z2) * w2v2 + ssp_fast(z3) * w2v3; \
    t += __shfl_xor(t, 1); t += __shfl_xor(t, 2); \
    t += __shfl_xor(t, 4); t += __shfl_xor(t, 8); \
    OUT = t; \
} while (0)

// Kernel A: per-edge MLP via bf16 MFMA. All per-tile state in NAMED registers
// (no runtime-indexed locals, no pointer casts — rule #20; scratch leak was
// the round-2..4 limiter). W1 bf16 fragment table in 16 KB LDS.
__global__ __launch_bounds__(256, 4) void mlp_mag_kernel(
    const float* __restrict__ feats,
    const float* __restrict__ w1,
    const float* __restrict__ b1,
    const float* __restrict__ w2,
    const float* __restrict__ b2,
    float* __restrict__ mag_raw,
    int E)
{
    __shared__ __align__(16) unsigned char smem[32768];
    float* w1s = (float*)smem;                 // transient: raw w1 (32 KB)
    bf16x8* hiTab = (bf16x8*)smem;             // final: bf16 frags (16 KB)

    const int lane = threadIdx.x & 63;
    const int r = lane & 15;
    const int g = lane >> 4;
    const int wave = blockIdx.x * (blockDim.x >> 6) + (threadIdx.x >> 6);
    const int nwaves = gridDim.x * (blockDim.x >> 6);

    // Stage B fragment table in LDS (once per block).
    for (int idx = threadIdx.x; idx < DFEAT * HDIM / 4; idx += blockDim.x)
        ((float4*)w1s)[idx] = ((const float4*)w1)[idx];
    __syncthreads();
    {
        const int tkt = threadIdx.x >> 6;      // this thread builds frags for k-chunk tkt
        const int tl = threadIdx.x & 63;
        const int tg = tl >> 4, tr = tl & 15;
        float vals[4][8];
#pragma unroll
        for (int nt = 0; nt < 4; ++nt)
#pragma unroll
            for (int i = 0; i < 8; ++i)
                vals[nt][i] = w1s[(tkt * 32 + tg * 8 + i) * HDIM + nt * 16 + tr];
        __syncthreads();                        // done reading raw w1; safe to overwrite
#pragma unroll
        for (int nt = 0; nt < 4; ++nt) {
            bf16x8 h;
#pragma unroll
            for (int i = 0; i < 8; ++i) h[i] = (__bf16)vals[nt][i];
            hiTab[(tkt * 4 + nt) * 64 + tl] = h;
        }
        __syncthreads();
    }

    const float b1v0 = b1[0 * 16 + r], b1v1 = b1[1 * 16 + r];
    const float b1v2 = b1[2 * 16 + r], b1v3 = b1[3 * 16 + r];
    const float w2v0 = w2[0 * 16 + r], w2v1 = w2[1 * 16 + r];
    const float w2v2 = w2[2 * 16 + r], w2v3 = w2[3 * 16 + r];
    const float b2v = b2[0];

    const int ntiles = (E + 15) >> 4;
    for (int tile = wave; tile < ntiles; tile += nwaves) {
        const int e0 = tile << 4;
        int er = e0 + r;
        if (er >= E) er = E - 1;           // clamp: loads stay valid; store is guarded

        const float4* fp = (const float4*)(feats + (size_t)er * DFEAT) + g * 2;
        float4 p0 = fp[0],  p1 = fp[1];
        float4 p2 = fp[8],  p3 = fp[9];
        float4 p4 = fp[16], p5 = fp[17];
        float4 p6 = fp[24], p7 = fp[25];

        f32x4 acc0 = {0.f,0.f,0.f,0.f}, acc1 = {0.f,0.f,0.f,0.f};
        f32x4 acc2 = {0.f,0.f,0.f,0.f}, acc3 = {0.f,0.f,0.f,0.f};
        KSTEP(p0, p1, 0);
        KSTEP(p2, p3, 1);
        KSTEP(p4, p5, 2);
        KSTEP(p6, p7, 3);

        float s0, s1, s2, s3;
        REDJ(0, s0); REDJ(1, s1); REDJ(2, s2); REDJ(3, s3);

        if (r < 4) {
            int e = e0 + g * 4 + r;
            if (e < E) {
                // 4-way select by r without a runtime-indexed array (cndmask chain)
                float sel = (r == 0) ? s0 : (r == 1) ? s1 : (r == 2) ? s2 : s3;
                mag_raw[e] = sel + b2v;
            }
        }
    }
}

// Kernel B: scatter-mean inputs via sorted-run segmented reduction.
// ~2 atomics per center-run instead of 2 per edge; correct even if unsorted.
__global__ __launch_bounds__(256) void bias_kernel(
    const void* __restrict__ eidx,
    const float* __restrict__ mag,
    float* __restrict__ csum,
    float* __restrict__ ccnt,
    const unsigned int* __restrict__ flag_any,
    int E)
{
    __shared__ int cs[256];
    __shared__ float ms[256];
    const int is64 = (flag_any[0] == 0u) ? 1 : 0;
    const int tloc = threadIdx.x;
    const int i = blockIdx.x * 256 + tloc;
    int c = -1; float m = 0.0f;
    if (i < E) { c = load_idx(eidx, is64, i); m = mag[i]; }
    cs[tloc] = c; ms[tloc] = m;
    __syncthreads();
    if (i < E) {
        bool leader = (tloc == 0) || (cs[tloc - 1] != c);
        if (leader) {
            float s = 0.0f; int n = 0; int j = tloc;
            int lim = min(256, E - blockIdx.x * 256);
            while (j < lim && cs[j] == c) { s += ms[j]; ++n; ++j; }
            atomicAdd(&csum[c], s);
            atomicAdd(&ccnt[c], (float)n);
        }
    }
}

// Kernel C: hash-join pairing (replaces argsort). The two directed copies of an
// undirected edge compute bitwise-identical keys (|(-v)/l| == |v/l| under IEEE),
// so an exact-match join reproduces the reference's sorted-pair grouping.
// Finisher debiases both, averages, and writes the avg IN PLACE into mag
// (each edge's slot is touched only by its own pair's finisher).
__global__ __launch_bounds__(256) void pair_kernel(
    const float* __restrict__ vec,
    const float* __restrict__ len,
    const void* __restrict__ eidx,
    float* __restrict__ mag,
    const float* __restrict__ csum,
    const float* __restrict__ ccnt,
    unsigned long long* __restrict__ tab,
    const unsigned int* __restrict__ flag_any,
    int E, int hash_bits)
{
    int i = blockIdx.x * blockDim.x + threadIdx.x;
    if (i >= E) return;
    const int is64 = (flag_any[0] == 0u) ? 1 : 0;

    float l = len[i];
    float ux = vec[3 * i + 0] / l;
    float uy = vec[3 * i + 1] / l;
    float uz = vec[3 * i + 2] / l;
    float s3 = (fabsf(ux) + fabsf(uy)) + fabsf(uz);

    int ci_ = load_idx(eidx, is64, i);
    int ni_ = load_idx(eidx, is64, (long long)E + i);

    long long key = (long long)ci_ + (long long)ni_
                  + (long long)(1.0e10f * l)
                  + (long long)(1.0e10f * s3);

    unsigned long long entry = ((unsigned long long)key << IDX_BITS) | (unsigned)i;
    unsigned long long h = (unsigned long long)key * 0x9E3779B97F4A7C15ull;
    unsigned slot = (unsigned)(h >> (64 - hash_bits));
    const unsigned smask = (1u << hash_bits) - 1u;

    int j;
    while (true) {
        unsigned long long old = atomicCAS(&tab[slot], EMPTY_SLOT, entry);
        if (old == EMPTY_SLOT) return;  // first arrival: partner finishes the job
        if ((old >> IDX_BITS) == (unsigned long long)key) {
            j = (int)(old & IDX_MASK);
            break;
        }
        slot = (slot + 1) & smask;
    }

    int cj_ = load_idx(eidx, is64, j);
    float mi = mag[i] - csum[ci_] / fmaxf(ccnt[ci_], 1.0f);
    float mj = mag[j] - csum[cj_] / fmaxf(ccnt[cj_], 1.0f);
    float avg = 0.5f * (mi + mj);
    mag[i] = avg;
    mag[j] = avg;
}

// Kernel D: edge_force = mag*unit, segment-sum by (sorted) center via run
// detection; ~3 atomics per run instead of 3 per edge. Correct if unsorted.
__global__ __launch_bounds__(256) void force_kernel(
    const float* __restrict__ vec,
    const float* __restrict__ len,
    const void* __restrict__ eidx,
    const float* __restrict__ mag,
    float* __restrict__ out,
    const unsigned int* __restrict__ flag_any,
    int E)
{
    __shared__ int cs[256];
    __shared__ float fx[256], fy[256], fz[256];
    const int is64 = (flag_any[0] == 0u) ? 1 : 0;
    const int tloc = threadIdx.x;
    const int i = blockIdx.x * 256 + tloc;
    int c = -1;
    if (i < E) {
        c = load_idx(eidx, is64, i);
        float l = len[i];
        float m = mag[i];
        fx[tloc] = m * vec[3 * i + 0] / l;
        fy[tloc] = m * vec[3 * i + 1] / l;
        fz[tloc] = m * vec[3 * i + 2] / l;
    }
    cs[tloc] = c;
    __syncthreads();
    if (i < E) {
        bool leader = (tloc == 0) || (cs[tloc - 1] != c);
        if (leader) {
            float sx = 0.f, sy = 0.f, sz = 0.f;
            int j = tloc;
            int lim = min(256, E - blockIdx.x * 256);
            while (j < lim && cs[j] == c) { sx += fx[j]; sy += fy[j]; sz += fz[j]; ++j; }
            atomicAdd(&out[c * 3 + 0], sx);
            atomicAdd(&out[c * 3 + 1], sy);
            atomicAdd(&out[c * 3 + 2], sz);
        }
    }
}

extern "C" void kernel_launch(void* const* d_in, const int* in_sizes, int n_in,
                              void* d_out, int out_size, void* d_ws, size_t ws_size,
                              hipStream_t stream) {
    const float* feats = (const float*)d_in[0];
    const float* vec   = (const float*)d_in[1];
    const float* len   = (const float*)d_in[2];
    const void*  eidx  = d_in[3];
    const float* w1 = (const float*)d_in[4];
    const float* b1 = (const float*)d_in[5];
    const float* w2 = (const float*)d_in[6];
    const float* b2 = (const float*)d_in[7];
    float* out = (float*)d_out;

    const int E = in_sizes[0] / DFEAT;
    const int N = out_size / 3;

    // Workspace: mag (E f32) | csum (N) | ccnt (N) | flag (256B) | tab
    char* ws = (char*)d_ws;
    size_t off_mag  = 0;
    size_t off_csum = (off_mag + (size_t)E * 4 + 255) & ~(size_t)255;
    size_t off_ccnt = off_csum + (size_t)N * 4;
    size_t off_flag = (off_ccnt + (size_t)N * 4 + 255) & ~(size_t)255;
    size_t off_tab  = off_flag + 256;

    float* mag     = (float*)(ws + off_mag);
    float* csum    = (float*)(ws + off_csum);
    float* ccnt    = (float*)(ws + off_ccnt);
    unsigned int* flag_any = (unsigned int*)(ws + off_flag);

    int hash_bits = 21;
    while (hash_bits > 20 && off_tab + (8ull << hash_bits) > ws_size) --hash_bits;
    unsigned long long* tab = (unsigned long long*)(ws + off_tab);

    // one contiguous memset covers csum | ccnt | flag
    hipMemsetAsync(csum, 0, off_flag + 256 - off_csum, stream);
    hipMemsetAsync(tab, 0xFF, (size_t)8 << hash_bits, stream);
    hipMemsetAsync(out, 0, (size_t)out_size * 4, stream);

    int n_check = E < 1024 ? E : 1024;
    detect_idx_kernel<<<1, 256, 0, stream>>>((const unsigned int*)eidx, n_check, flag_any);

    mlp_mag_kernel<<<1024, 256, 0, stream>>>(feats, w1, b1, w2, b2, mag, E);

    int eblocks = (E + 255) / 256;
    bias_kernel<<<eblocks, 256, 0, stream>>>(eidx, mag, csum, ccnt, flag_any, E);
    pair_kernel<<<eblocks, 256, 0, stream>>>(vec, len, eidx, mag, csum, ccnt,
                                             tab, flag_any, E, hash_bits);
    force_kernel<<<eblocks, 256, 0, stream>>>(vec, len, eidx, mag, out, flag_any, E);
}